// Round 1
// baseline (180.123 us; speedup 1.0000x reference)
//
#include <hip/hip_runtime.h>

// SkipGram negative-sampling loss on MI355X.
// B=16384 elements, 74 labels each (10 pos + 64 neg), EMB=128 f32.
// One wave per batch element; 4 labels processed concurrently by 4
// 16-lane groups (each lane owns 8 contiguous dims = 2x float4).

#define VOCAB  100000
#define EMB    128
#define B_TOT  16384
#define W_POS  10
#define K_NEG  64
#define N_LAB  (W_POS + K_NEG)   // 74

__device__ __forceinline__ float logsig(float x) {
    // jax.nn.log_sigmoid: -softplus(-x) = min(x,0) - log1p(exp(-|x|))
    return fminf(x, 0.0f) - log1pf(__expf(-fabsf(x)));
}

__global__ __launch_bounds__(256) void skipgram_kernel(
    const int*   __restrict__ input,       // [B]
    const int*   __restrict__ pos_labels,  // [B, W_POS]
    const int*   __restrict__ neg_labels,  // [B, K_NEG]
    const float* __restrict__ input_emb,   // [VOCAB, EMB]
    const float* __restrict__ output_emb,  // [VOCAB, EMB]
    float*       __restrict__ out)         // [1]
{
    const int lane = threadIdx.x & 63;
    const int gl   = lane & 15;   // lane within 16-lane group
    const int grp  = lane >> 4;   // which of 4 labels this lane serves
    const int wave   = (int)((blockIdx.x * blockDim.x + threadIdx.x) >> 6);
    const int nwaves = (int)((gridDim.x * blockDim.x) >> 6);

    float acc = 0.0f;  // sum of logsigmoid over this wave's elements (on gl==0 lanes)

    for (int b = wave; b < B_TOT; b += nwaves) {
        const int c = input[b];
        const float4* crow = (const float4*)(input_emb + (size_t)c * EMB);
        const float4 c0 = crow[gl * 2];
        const float4 c1 = crow[gl * 2 + 1];

        const int* pl = pos_labels + b * W_POS;
        const int* nl = neg_labels + b * K_NEG;

        for (int t = 0; t < N_LAB; t += 4) {
            const int  j     = t + grp;
            const bool valid = (j < N_LAB);
            int r = 0;
            if (valid) r = (j < W_POS) ? pl[j] : nl[j - W_POS];
            const float4* row = (const float4*)(output_emb + (size_t)r * EMB);
            const float4 a0 = row[gl * 2];
            const float4 a1 = row[gl * 2 + 1];

            float p = a0.x * c0.x + a0.y * c0.y + a0.z * c0.z + a0.w * c0.w
                    + a1.x * c1.x + a1.y * c1.y + a1.z * c1.z + a1.w * c1.w;

            // reduce the 16-lane group's partials -> full 128-dim dot
            p += __shfl_xor(p, 1);
            p += __shfl_xor(p, 2);
            p += __shfl_xor(p, 4);
            p += __shfl_xor(p, 8);

            if (valid && gl == 0) acc += logsig(p);
        }
    }

    // combine the 4 group accumulators (lanes 0,16,32,48) -> lane 0
    acc += __shfl_xor(acc, 16);
    acc += __shfl_xor(acc, 32);

    if (lane == 0) atomicAdd(out, -acc);
}

extern "C" void kernel_launch(void* const* d_in, const int* in_sizes, int n_in,
                              void* d_out, int out_size, void* d_ws, size_t ws_size,
                              hipStream_t stream) {
    const int*   input      = (const int*)  d_in[0];
    const int*   pos_labels = (const int*)  d_in[1];
    const int*   neg_labels = (const int*)  d_in[2];
    const float* input_emb  = (const float*)d_in[3];
    const float* output_emb = (const float*)d_in[4];
    float*       out        = (float*)      d_out;

    // d_out is poisoned (0xAA) and not re-zeroed between replays.
    hipMemsetAsync(out, 0, sizeof(float), stream);

    // 2048 blocks x 256 threads = 8192 waves -> 2 batch elements per wave.
    dim3 grid(2048), block(256);
    hipLaunchKernelGGL(skipgram_kernel, grid, block, 0, stream,
                       input, pos_labels, neg_labels, input_emb, output_emb, out);
}